// Round 10
// baseline (319.446 us; speedup 1.0000x reference)
//
#include <hip/hip_runtime.h>

#define FEAT 128
#define HID  100
#define CHUNK 4096   // edges per block in hist/scatter passes

typedef __attribute__((ext_vector_type(8))) short short8;
typedef __attribute__((ext_vector_type(4))) float f32x4;

// RNE f32 -> bf16
__device__ __forceinline__ unsigned short f2bf(float f) {
    union { float f; unsigned int u; } v; v.f = f;
    unsigned int r = v.u + 0x7fffu + ((v.u >> 16) & 1u);
    return (unsigned short)(r >> 16);
}

__device__ __forceinline__ int get_edge(const void* ei, int f64, long long pos) {
    return f64 ? (int)((const long long*)ei)[pos] : ((const int*)ei)[pos];
}

// per-wave int64 staging detection: int64 => all sampled high words are 0.
// Must be called with all lanes of the wave active (before any early return).
__device__ __forceinline__ int detect_f64(const void* ei) {
    const int* p = (const int*)ei;
    unsigned long long b = __ballot(p[2 * (threadIdx.x & 63) + 1] == 0);
    return b == ~0ull;
}

// ---------------- k_front: cvt + fold + bucket-histogram in ONE dispatch ------
// blocks [0,1024): x->bf16 | [1024,1154): weight fold | [1154,1154+nblocksA): hist
__global__ __launch_bounds__(256)
void k_front(const float* __restrict__ x, uint4* __restrict__ xb, int n8,
             const float* __restrict__ Wcz, const float* __restrict__ bcz,
             const float* __restrict__ Wch, const float* __restrict__ bch,
             const float* __restrict__ Wlz, const float* __restrict__ blz,
             const float* __restrict__ Wlh, const float* __restrict__ blh,
             const float* __restrict__ Wout,
             unsigned short* __restrict__ WB, float* __restrict__ bfold_ext,
             float* __restrict__ WoutZ,
             const void* ei, int* __restrict__ bucketCnt,
             int* __restrict__ blockBase, int NB, int E) {
    const int CVTB = 1024, FOLDB = 130;
    __shared__ int hist[1024];
    if (blockIdx.x < CVTB) {
        int stride = CVTB * 256;
        for (int i = blockIdx.x * 256 + threadIdx.x; i < n8; i += stride) {
            float4 a = *(const float4*)(x + (size_t)i * 8);
            float4 b = *(const float4*)(x + (size_t)i * 8 + 4);
            uint4 o;
            o.x = f2bf(a.x) | ((unsigned)f2bf(a.y) << 16);
            o.y = f2bf(a.z) | ((unsigned)f2bf(a.w) << 16);
            o.z = f2bf(b.x) | ((unsigned)f2bf(b.y) << 16);
            o.w = f2bf(b.z) | ((unsigned)f2bf(b.w) << 16);
            xb[i] = o;
        }
        return;
    }
    if (blockIdx.x < CVTB + FOLDB) {
        int idx = (blockIdx.x - CVTB) * 256 + threadIdx.x;
        if (idx < FEAT * 256) {
            int k = idx >> 8, n = idx & 255;
            float val = 0.f;
            if (n < HID) {
                for (int m = 0; m < HID; m++) val += Wcz[k * HID + m] * Wlz[m * HID + n];
            } else if (n >= 128 && n < 128 + HID) {
                int c = n - 128;
                for (int m = 0; m < HID; m++) val += Wch[k * HID + m] * Wlh[m * HID + c];
            }
            int ni = n >> 4, lc = n & 15, ks = k >> 5, hi = (k >> 3) & 3, j = k & 7;
            WB[(((ni * 4 + ks) * 64 + hi * 16 + lc) << 3) + j] = f2bf(val);
        } else if (idx < FEAT * 256 + 256) {
            int c = idx - FEAT * 256;
            float v = 0.f;
            if (c < HID) {
                v = blz[c];
                for (int j = 0; j < HID; j++) v += bcz[j] * Wlz[j * HID + c];
            } else if (c >= 128 && c < 128 + HID) {
                int cc = c - 128;
                v = blh[cc];
                for (int j = 0; j < HID; j++) v += bch[j] * Wlh[j * HID + cc];
            }
            bfold_ext[c] = v;
        } else if (idx < FEAT * 256 + 256 + 128) {
            int c = idx - FEAT * 256 - 256;
            WoutZ[c] = (c < HID) ? Wout[c] : 0.f;
        }
        return;
    }
    // ---- histogram part: bucket = dst>>8; 1 global atomic per (block,bucket)
    int f64 = detect_f64(ei);
    int cb = blockIdx.x - CVTB - FOLDB;
    int t = threadIdx.x;
    for (int i = t; i < NB; i += 256) hist[i] = 0;
    __syncthreads();
    int e0 = cb * CHUNK;
#pragma unroll
    for (int k = 0; k < CHUNK / 256; k++) {
        int e = e0 + k * 256 + t;
        if (e < E) {
            int d = get_edge(ei, f64, (long long)E + e);
            atomicAdd(&hist[d >> 8], 1);
        }
    }
    __syncthreads();
    int* bb = blockBase + (size_t)cb * NB;
    for (int b = t; b < NB; b += 256) {
        int c = hist[b];
        if (c) bb[b] = atomicAdd(&bucketCnt[b], c);
    }
}

// ---------------- scan of bucket counts (NB <= 1024) --------------------------
__global__ void k_scanb(const int* __restrict__ bucketCnt, int* __restrict__ bucketStart,
                        int NB) {
    __shared__ int lds[1024];
    int t = threadIdx.x;
    int v = (t < NB) ? bucketCnt[t] : 0;
    lds[t] = v;
    __syncthreads();
    for (int off = 1; off < 1024; off <<= 1) {
        int tv = (t >= off) ? lds[t - off] : 0;
        __syncthreads();
        lds[t] += tv;
        __syncthreads();
    }
    if (t < NB) bucketStart[t] = lds[t] - v;   // exclusive
    if (t == NB - 1) bucketStart[NB] = lds[t]; // sentinel = E
}

// ---------------- A2: scatter edges into bucket regions (no global atomics) ---
// entry: (src | dlow<<24, w_bits)
__global__ __launch_bounds__(256)
void k_scatter(const void* ei, const float* __restrict__ w,
               const int* __restrict__ bucketStart, const int* __restrict__ blockBase,
               int2* __restrict__ sc, int NB, int E) {
    int f64 = detect_f64(ei);
    __shared__ int hist[1024];
    int t = threadIdx.x;
    for (int i = t; i < NB; i += 256) hist[i] = 0;
    __syncthreads();
    int e0 = blockIdx.x * CHUNK;
    const int* bb = blockBase + (size_t)blockIdx.x * NB;
#pragma unroll
    for (int k = 0; k < CHUNK / 256; k++) {
        int e = e0 + k * 256 + t;
        if (e < E) {
            int s = get_edge(ei, f64, e);
            int d = get_edge(ei, f64, (long long)E + e);
            int b = d >> 8;
            int r = atomicAdd(&hist[b], 1);
            int pos = bucketStart[b] + bb[b] + r;
            long long val = ((long long)__float_as_int(w[e]) << 32)
                          | (unsigned)(s | ((d & 255) << 24));
            __builtin_nontemporal_store(val, (long long*)&sc[pos]);
        }
    }
}

// ---------------- B: per-bucket exact CSR + degsum + self entry ---------------
__global__ __launch_bounds__(256)
void k_bucket(const int2* __restrict__ sc, const int* __restrict__ bucketStart,
              int* __restrict__ offs, int* __restrict__ cnt,
              int2* __restrict__ csr, float* __restrict__ dinv, int N) {
    __shared__ int hist[256];
    __shared__ int offsL[256];
    __shared__ int rank[256];
    __shared__ float wsum[256];
    int t = threadIdx.x;
    int n0 = blockIdx.x << 8;
    int s = bucketStart[blockIdx.x], e = bucketStart[blockIdx.x + 1];
    hist[t] = 0;
    rank[t] = 0;
    wsum[t] = 0.f;
    __syncthreads();
    for (int i = s + t; i < e; i += 256)
        atomicAdd(&hist[((unsigned)sc[i].x) >> 24], 1);
    __syncthreads();
    int v = (n0 + t < N) ? hist[t] + 1 : 0;   // +1 self-loop slot per real node
    offsL[t] = v;
    __syncthreads();
    for (int off = 1; off < 256; off <<= 1) {
        int tv = (t >= off) ? offsL[t - off] : 0;
        __syncthreads();
        offsL[t] += tv;
        __syncthreads();
    }
    int myOff = offsL[t] - v;                 // exclusive
    int csrBase = s + n0;                     // edge start + self slots of prior buckets
    if (n0 + t < N) {
        offs[n0 + t] = csrBase + myOff;
        cnt[n0 + t] = v;
    }
    offsL[t] = myOff;                         // exclusive, for scatter
    __syncthreads();
    for (int i = s + t; i < e; i += 256) {
        int2 en = sc[i];
        int dlow = ((unsigned)en.x) >> 24;
        int r = atomicAdd(&rank[dlow], 1);
        csr[csrBase + offsL[dlow] + r] = make_int2(en.x & 0xFFFFFF, en.y);
        atomicAdd(&wsum[dlow], __int_as_float(en.y));
    }
    __syncthreads();
    if (n0 + t < N) {
        dinv[n0 + t] = rsqrtf(1.f + wsum[t]);
        // self entry at end of row (slot myOff + hist[t])
        csr[csrBase + myOff + hist[t]] = make_int2(n0 + t, __float_as_int(1.0f));
    }
}

// ---------------- aggregation: wave/node, 8 edges in flight, bf16 gathers -----
// aggx[d] = dinv[d] * sum_e w_e*dinv[s_e]*x[s_e]  over nodes [nlo, nhi)
__global__ __launch_bounds__(256)
void k_agg4(const unsigned short* __restrict__ xb, const float* __restrict__ dinv,
            const int* __restrict__ offs, const int* __restrict__ cnt,
            const int2* __restrict__ csr, unsigned short* __restrict__ aggx,
            int nlo, int nhi) {
    int wid  = __builtin_amdgcn_readfirstlane(threadIdx.x >> 6);
    int lane = threadIdx.x & 63;
    long long node = (long long)nlo + blockIdx.x * 4 + wid;
    if (node >= nhi) return;
    int q  = lane >> 3;        // edge slot 0..7
    int fl = lane & 7;         // feature group: floats fl*16 .. fl*16+15
    float acc[16];
#pragma unroll
    for (int j = 0; j < 16; j++) acc[j] = 0.f;
    int rs = offs[node];
    int c  = cnt[node];
    for (int i = q; i < c; i += 8) {
        int2 e = csr[rs + i];
        float nr = __int_as_float(e.y) * dinv[e.x];   // w * dinv[src]
        const uint4* xp = (const uint4*)(xb + (size_t)e.x * FEAT + fl * 16);
        uint4 v0 = xp[0];
        uint4 v1 = xp[1];
        const unsigned* u0 = &v0.x;
        const unsigned* u1 = &v1.x;
#pragma unroll
        for (int j = 0; j < 4; j++) {
            acc[2*j]         += nr * __uint_as_float(u0[j] << 16);
            acc[2*j + 1]     += nr * __uint_as_float(u0[j] & 0xffff0000u);
            acc[8 + 2*j]     += nr * __uint_as_float(u1[j] << 16);
            acc[8 + 2*j + 1] += nr * __uint_as_float(u1[j] & 0xffff0000u);
        }
    }
#pragma unroll
    for (int j = 0; j < 16; j++) {
        acc[j] += __shfl_xor(acc[j], 8);
        acc[j] += __shfl_xor(acc[j], 16);
        acc[j] += __shfl_xor(acc[j], 32);
    }
    if (q == 0) {
        float dn = dinv[node];
        uint4 o0, o1;
        unsigned* p0 = &o0.x;
        unsigned* p1 = &o1.x;
#pragma unroll
        for (int j = 0; j < 4; j++) {
            p0[j] = f2bf(acc[2*j] * dn)   | ((unsigned)f2bf(acc[2*j+1] * dn) << 16);
            p1[j] = f2bf(acc[8+2*j] * dn) | ((unsigned)f2bf(acc[8+2*j+1] * dn) << 16);
        }
        uint4* op = (uint4*)(aggx + (size_t)node * FEAT + fl * 16);
        op[0] = o0;
        op[1] = o1;
    }
}

// ---------------- MFMA GEMM + gates + output, 64 nodes per block --------------
__global__ __launch_bounds__(256)
void k_post3(const unsigned short* __restrict__ aggx, const unsigned short* __restrict__ WB,
             const float* __restrict__ bfold_ext, const float* __restrict__ WoutZ,
             const float* __restrict__ bout, float* __restrict__ out, int N) {
    __shared__ unsigned short At[64 * 136];   // 128 + 8 pad
    __shared__ float red[64 * 4];
    int t = threadIdx.x;
    int lane = t & 63;
    int w = __builtin_amdgcn_readfirstlane(t >> 6);
    long long base = (long long)blockIdx.x * 64;

    for (int it = 0; it < 4; it++) {
        int idx = it * 256 + t;
        int row = idx >> 4, c16 = idx & 15;
        long long grow = base + row;
        uint4 v = make_uint4(0u, 0u, 0u, 0u);
        if (grow < N) v = *(const uint4*)(aggx + grow * FEAT + c16 * 8);
        *(uint4*)(At + row * 136 + c16 * 8) = v;
    }
    __syncthreads();

    int l15 = lane & 15, lhi = lane >> 4;
    int tadd = 2 * w;
    f32x4 acc[4][4];
#pragma unroll
    for (int ti = 0; ti < 4; ti++)
#pragma unroll
        for (int mi = 0; mi < 4; mi++) acc[ti][mi] = (f32x4)0.f;

    const int tiles[4] = {tadd, tadd + 1, tadd + 8, tadd + 9};
#pragma unroll
    for (int ks = 0; ks < 4; ks++) {
        short8 a[4];
#pragma unroll
        for (int mi = 0; mi < 4; mi++)
            a[mi] = *(const short8*)(At + (mi * 16 + l15) * 136 + ks * 32 + lhi * 8);
        short8 b[4];
#pragma unroll
        for (int ti = 0; ti < 4; ti++)
            b[ti] = *(const short8*)(WB + (((tiles[ti] * 4 + ks) * 64 + lane) << 3));
#pragma unroll
        for (int ti = 0; ti < 4; ti++)
#pragma unroll
            for (int mi = 0; mi < 4; mi++)
                acc[ti][mi] = __builtin_amdgcn_mfma_f32_16x16x32_bf16(
                    a[mi], b[ti], acc[ti][mi], 0, 0, 0);
    }

    float partial[4][4];
#pragma unroll
    for (int mi = 0; mi < 4; mi++)
#pragma unroll
        for (int r = 0; r < 4; r++) partial[mi][r] = 0.f;
#pragma unroll
    for (int d = 0; d < 2; d++) {
        int zcol = (tadd + d) * 16 + l15;
        float bz = bfold_ext[zcol];
        float bh = bfold_ext[zcol + 128];
        float wo = WoutZ[zcol];
#pragma unroll
        for (int mi = 0; mi < 4; mi++)
#pragma unroll
            for (int r = 0; r < 4; r++) {
                float az = acc[d][mi][r] + bz;
                float ah = acc[d + 2][mi][r] + bh;
                float z  = 1.f / (1.f + expf(-az));
                float ht = tanhf(ah);
                float h  = (1.f - z) * ht;
                h = h > 0.f ? h : 0.f;
                partial[mi][r] += h * wo;
            }
    }
#pragma unroll
    for (int mi = 0; mi < 4; mi++)
#pragma unroll
        for (int r = 0; r < 4; r++) {
            float p = partial[mi][r];
            p += __shfl_xor(p, 1);
            p += __shfl_xor(p, 2);
            p += __shfl_xor(p, 4);
            p += __shfl_xor(p, 8);
            partial[mi][r] = p;
        }
    if (l15 == 0) {
#pragma unroll
        for (int mi = 0; mi < 4; mi++)
#pragma unroll
            for (int r = 0; r < 4; r++)
                red[(mi * 16 + lhi * 4 + r) * 4 + w] = partial[mi][r];
    }
    __syncthreads();
    if (t < 64) {
        long long node = base + t;
        if (node < N)
            out[node] = red[t * 4] + red[t * 4 + 1] + red[t * 4 + 2] + red[t * 4 + 3]
                      + bout[0];
    }
}

// ---------------- launcher ----------------
extern "C" void kernel_launch(void* const* d_in, const int* in_sizes, int n_in,
                              void* d_out, int out_size, void* d_ws, size_t ws_size,
                              hipStream_t stream) {
    const float* x    = (const float*)d_in[0];
    const void*  ei   = d_in[1];
    const float* ew   = (const float*)d_in[2];
    const float* Wcz  = (const float*)d_in[3];
    const float* bcz  = (const float*)d_in[4];
    // d_in[5], d_in[6] (Wcr, bcr) dead: R only multiplies H0 == 0
    const float* Wch  = (const float*)d_in[7];
    const float* bch  = (const float*)d_in[8];
    const float* Wlz  = (const float*)d_in[9];
    const float* blz  = (const float*)d_in[10];
    // d_in[11], d_in[12] (Wlr, blr) dead too
    const float* Wlh  = (const float*)d_in[13];
    const float* blh  = (const float*)d_in[14];
    const float* Wout = (const float*)d_in[15];
    const float* bout = (const float*)d_in[16];
    float* out = (float*)d_out;

    int N = in_sizes[0] / FEAT;   // 100000
    int E = in_sizes[2];          // 1600000
    int NB = (N + 255) >> 8;      // 391 buckets of 256 nodes (NB <= 1024)
    int nblocksA = (E + CHUNK - 1) / CHUNK;   // 391

    char* p = (char*)d_ws;
    auto alloc = [&](size_t bytes) -> char* {
        char* r = p;
        p += (bytes + 255) & ~(size_t)255;
        return r;
    };
    float*          dinv        = (float*)alloc((size_t)N * 4);
    int*            cnt         = (int*)  alloc((size_t)N * 4);
    int*            offs        = (int*)  alloc((size_t)N * 4);
    int*            bucketCnt   = (int*)  alloc((size_t)(NB + 1) * 4);
    int*            bucketStart = (int*)  alloc((size_t)(NB + 1) * 4);
    int2*           csr         = (int2*) alloc((size_t)(E + N) * 8);
    unsigned short* xb          = (unsigned short*)alloc((size_t)N * FEAT * 2);
    unsigned short* aggx        = (unsigned short*)alloc((size_t)N * FEAT * 2);
    unsigned short* WB          = (unsigned short*)alloc((size_t)FEAT * 256 * 2);
    float*          bfold_ext   = (float*)alloc(256 * 4);
    float*          WoutZ       = (float*)alloc(128 * 4);
    // aliases into aggx (disjoint lifetimes: sc dead after k_bucket, blockBase
    // dead after k_scatter; aggx first written by k_agg4 afterwards)
    int2* sc        = (int2*)aggx;                       // E*8 <= N*256 bytes
    int*  blockBase = (int*)((char*)aggx + (size_t)E * 8);  // nblocksA*NB*4

    hipMemsetAsync(bucketCnt, 0, (size_t)NB * 4, stream);
    k_front<<<1024 + 130 + nblocksA, 256, 0, stream>>>(
        x, (uint4*)xb, N * FEAT / 8,
        Wcz, bcz, Wch, bch, Wlz, blz, Wlh, blh, Wout, WB, bfold_ext, WoutZ,
        ei, bucketCnt, blockBase, NB, E);
    k_scanb<<<1, 1024, 0, stream>>>(bucketCnt, bucketStart, NB);
    k_scatter<<<nblocksA, 256, 0, stream>>>(ei, ew, bucketStart, blockBase, sc, NB, E);
    k_bucket<<<NB, 256, 0, stream>>>(sc, bucketStart, offs, cnt, csr, dinv, N);
    int N2 = 50000;  // split agg for profiler visibility (N2 % 4 == 0)
    k_agg4<<<(N2 + 3) / 4, 256, 0, stream>>>(xb, dinv, offs, cnt, csr, aggx, 0, N2);
    k_agg4<<<(N - N2 + 3) / 4, 256, 0, stream>>>(xb, dinv, offs, cnt, csr, aggx, N2, N);
    k_post3<<<(N + 63) / 64, 256, 0, stream>>>(aggx, WB, bfold_ext, WoutZ, bout, out, N);
}

// Round 11
// 295.791 us; speedup vs baseline: 1.0800x; 1.0800x over previous
//
#include <hip/hip_runtime.h>

#define FEAT 128
#define HID  100
#define CHUNK 2048   // edges per chunk-block in hist/scatter passes

typedef __attribute__((ext_vector_type(8))) short short8;
typedef __attribute__((ext_vector_type(4))) float f32x4;

// RNE f32 -> bf16
__device__ __forceinline__ unsigned short f2bf(float f) {
    union { float f; unsigned int u; } v; v.f = f;
    unsigned int r = v.u + 0x7fffu + ((v.u >> 16) & 1u);
    return (unsigned short)(r >> 16);
}

__device__ __forceinline__ int get_edge(const void* ei, int f64, long long pos) {
    return f64 ? (int)((const long long*)ei)[pos] : ((const int*)ei)[pos];
}

// per-wave int64 staging detection: int64 => all sampled high words are 0.
// Must be called with all lanes of the wave active (before any early return).
__device__ __forceinline__ int detect_f64(const void* ei) {
    const int* p = (const int*)ei;
    unsigned long long b = __ballot(p[2 * (threadIdx.x & 63) + 1] == 0);
    return b == ~0ull;
}

// ---------------- k_front: cvt + fold + bucket-histogram in ONE dispatch ------
// blocks [0,1024): x->bf16 | [1024,1154): weight fold | [1154,1154+nblocksA): hist
__global__ __launch_bounds__(256)
void k_front(const float* __restrict__ x, uint4* __restrict__ xb, int n8,
             const float* __restrict__ Wcz, const float* __restrict__ bcz,
             const float* __restrict__ Wch, const float* __restrict__ bch,
             const float* __restrict__ Wlz, const float* __restrict__ blz,
             const float* __restrict__ Wlh, const float* __restrict__ blh,
             const float* __restrict__ Wout,
             unsigned short* __restrict__ WB, float* __restrict__ bfold_ext,
             float* __restrict__ WoutZ,
             const void* ei, int* __restrict__ bucketCnt,
             int* __restrict__ blockBase, int NB, int E) {
    const int CVTB = 1024, FOLDB = 130;
    __shared__ int hist[1024];
    if (blockIdx.x < CVTB) {
        int stride = CVTB * 256;
        for (int i = blockIdx.x * 256 + threadIdx.x; i < n8; i += stride) {
            float4 a = *(const float4*)(x + (size_t)i * 8);
            float4 b = *(const float4*)(x + (size_t)i * 8 + 4);
            uint4 o;
            o.x = f2bf(a.x) | ((unsigned)f2bf(a.y) << 16);
            o.y = f2bf(a.z) | ((unsigned)f2bf(a.w) << 16);
            o.z = f2bf(b.x) | ((unsigned)f2bf(b.y) << 16);
            o.w = f2bf(b.z) | ((unsigned)f2bf(b.w) << 16);
            xb[i] = o;
        }
        return;
    }
    if (blockIdx.x < CVTB + FOLDB) {
        int idx = (blockIdx.x - CVTB) * 256 + threadIdx.x;
        if (idx < FEAT * 256) {
            int k = idx >> 8, n = idx & 255;
            float val = 0.f;
            if (n < HID) {
                for (int m = 0; m < HID; m++) val += Wcz[k * HID + m] * Wlz[m * HID + n];
            } else if (n >= 128 && n < 128 + HID) {
                int c = n - 128;
                for (int m = 0; m < HID; m++) val += Wch[k * HID + m] * Wlh[m * HID + c];
            }
            int ni = n >> 4, lc = n & 15, ks = k >> 5, hi = (k >> 3) & 3, j = k & 7;
            WB[(((ni * 4 + ks) * 64 + hi * 16 + lc) << 3) + j] = f2bf(val);
        } else if (idx < FEAT * 256 + 256) {
            int c = idx - FEAT * 256;
            float v = 0.f;
            if (c < HID) {
                v = blz[c];
                for (int j = 0; j < HID; j++) v += bcz[j] * Wlz[j * HID + c];
            } else if (c >= 128 && c < 128 + HID) {
                int cc = c - 128;
                v = blh[cc];
                for (int j = 0; j < HID; j++) v += bch[j] * Wlh[j * HID + cc];
            }
            bfold_ext[c] = v;
        } else if (idx < FEAT * 256 + 256 + 128) {
            int c = idx - FEAT * 256 - 256;
            WoutZ[c] = (c < HID) ? Wout[c] : 0.f;
        }
        return;
    }
    // ---- histogram part: bucket = dst>>8; 1 global atomic per (block,bucket)
    int f64 = detect_f64(ei);
    int cb = blockIdx.x - CVTB - FOLDB;
    int t = threadIdx.x;
    for (int i = t; i < NB; i += 256) hist[i] = 0;
    __syncthreads();
    int e0 = cb * CHUNK;
#pragma unroll
    for (int k = 0; k < CHUNK / 256; k++) {
        int e = e0 + k * 256 + t;
        if (e < E) {
            int d = get_edge(ei, f64, (long long)E + e);
            atomicAdd(&hist[d >> 8], 1);
        }
    }
    __syncthreads();
    int* bb = blockBase + (size_t)cb * NB;
    for (int b = t; b < NB; b += 256) {
        int c = hist[b];
        if (c) bb[b] = atomicAdd(&bucketCnt[b], c);
    }
}

// ---------------- scan of bucket counts (NB <= 1024) --------------------------
__global__ void k_scanb(const int* __restrict__ bucketCnt, int* __restrict__ bucketStart,
                        int NB) {
    __shared__ int lds[1024];
    int t = threadIdx.x;
    int v = (t < NB) ? bucketCnt[t] : 0;
    lds[t] = v;
    __syncthreads();
    for (int off = 1; off < 1024; off <<= 1) {
        int tv = (t >= off) ? lds[t - off] : 0;
        __syncthreads();
        lds[t] += tv;
        __syncthreads();
    }
    if (t < NB) bucketStart[t] = lds[t] - v;   // exclusive
    if (t == NB - 1) bucketStart[NB] = lds[t]; // sentinel = E
}

// ---------------- A2: scatter into bucket regions, MLP-4, cache-resident ------
// entry: (src | dlow<<24, w_bits). 512 threads, 4 edges/thread.
__global__ __launch_bounds__(512)
void k_scatter(const void* ei, const float* __restrict__ w,
               const int* __restrict__ bucketStart, const int* __restrict__ blockBase,
               int2* __restrict__ sc, int NB, int E) {
    int f64 = detect_f64(ei);
    __shared__ int hist[1024];
    int t = threadIdx.x;
    for (int i = t; i < NB; i += 512) hist[i] = 0;
    __syncthreads();
    int e0 = blockIdx.x * CHUNK;
    const int* bb = blockBase + (size_t)blockIdx.x * NB;
    int sA[4], dA[4], wA[4], ok[4];
#pragma unroll
    for (int k = 0; k < 4; k++) {           // phase 1: issue all loads
        int e = e0 + k * 512 + t;
        ok[k] = (e < E);
        if (ok[k]) {
            sA[k] = get_edge(ei, f64, e);
            dA[k] = get_edge(ei, f64, (long long)E + e);
            wA[k] = __float_as_int(w[e]);
        }
    }
#pragma unroll
    for (int k = 0; k < 4; k++) {           // phase 2: ranks + independent stores
        if (ok[k]) {
            int b = dA[k] >> 8;
            int r = atomicAdd(&hist[b], 1);
            int pos = bucketStart[b] + bb[b] + r;
            long long val = ((long long)wA[k] << 32)
                          | (unsigned)(sA[k] | ((dA[k] & 255) << 24));
            *(long long*)&sc[pos] = val;    // regular store: stays L2/L3-resident
        }
    }
}

// ---------------- B: per-bucket exact CSR + degsum + self entry (512 thr) -----
__global__ __launch_bounds__(512)
void k_bucket(const int2* __restrict__ sc, const int* __restrict__ bucketStart,
              int* __restrict__ offs, int* __restrict__ cnt,
              int2* __restrict__ csr, float* __restrict__ dinv, int N) {
    __shared__ int hist[256];
    __shared__ int offsL[256];
    __shared__ int rank[256];
    __shared__ float wsum[256];
    int t = threadIdx.x;
    int n0 = blockIdx.x << 8;
    int s = bucketStart[blockIdx.x], e = bucketStart[blockIdx.x + 1];
    if (t < 256) { hist[t] = 0; rank[t] = 0; wsum[t] = 0.f; }
    __syncthreads();
    for (int i = s + t; i < e; i += 512)
        atomicAdd(&hist[((unsigned)sc[i].x) >> 24], 1);
    __syncthreads();
    int v = 0;
    if (t < 256) {
        v = (n0 + t < N) ? hist[t] + 1 : 0;   // +1 self-loop slot per real node
        offsL[t] = v;
    }
    __syncthreads();
    for (int off = 1; off < 256; off <<= 1) {
        int tv = (t < 256 && t >= off) ? offsL[t - off] : 0;
        __syncthreads();
        if (t < 256) offsL[t] += tv;
        __syncthreads();
    }
    int myOff = 0, myHist = 0;
    if (t < 256) { myOff = offsL[t] - v; myHist = hist[t]; }
    int csrBase = s + n0;                     // edges + self slots of prior buckets
    if (t < 256 && n0 + t < N) {
        offs[n0 + t] = csrBase + myOff;
        cnt[n0 + t] = v;
    }
    __syncthreads();
    if (t < 256) offsL[t] = myOff;            // exclusive, for scatter
    __syncthreads();
    for (int i = s + t; i < e; i += 512) {
        int2 en = sc[i];
        int dlow = ((unsigned)en.x) >> 24;
        int r = atomicAdd(&rank[dlow], 1);
        csr[csrBase + offsL[dlow] + r] = make_int2(en.x & 0xFFFFFF, en.y);
        atomicAdd(&wsum[dlow], __int_as_float(en.y));
    }
    __syncthreads();
    if (t < 256 && n0 + t < N) {
        dinv[n0 + t] = rsqrtf(1.f + wsum[t]);
        csr[csrBase + myOff + myHist] = make_int2(n0 + t, __float_as_int(1.0f));
    }
}

// ---------------- aggregation: wave/node, 8 edges in flight, bf16 gathers -----
// aggx[d] = dinv[d] * sum_e w_e*dinv[s_e]*x[s_e]  over nodes [nlo, nhi)
__global__ __launch_bounds__(256)
void k_agg4(const unsigned short* __restrict__ xb, const float* __restrict__ dinv,
            const int* __restrict__ offs, const int* __restrict__ cnt,
            const int2* __restrict__ csr, unsigned short* __restrict__ aggx,
            int nlo, int nhi) {
    int wid  = __builtin_amdgcn_readfirstlane(threadIdx.x >> 6);
    int lane = threadIdx.x & 63;
    long long node = (long long)nlo + blockIdx.x * 4 + wid;
    if (node >= nhi) return;
    int q  = lane >> 3;        // edge slot 0..7
    int fl = lane & 7;         // feature group: floats fl*16 .. fl*16+15
    float acc[16];
#pragma unroll
    for (int j = 0; j < 16; j++) acc[j] = 0.f;
    int rs = offs[node];
    int c  = cnt[node];
    for (int i = q; i < c; i += 8) {
        int2 e = csr[rs + i];
        float nr = __int_as_float(e.y) * dinv[e.x];   // w * dinv[src]
        const uint4* xp = (const uint4*)(xb + (size_t)e.x * FEAT + fl * 16);
        uint4 v0 = xp[0];
        uint4 v1 = xp[1];
        const unsigned* u0 = &v0.x;
        const unsigned* u1 = &v1.x;
#pragma unroll
        for (int j = 0; j < 4; j++) {
            acc[2*j]         += nr * __uint_as_float(u0[j] << 16);
            acc[2*j + 1]     += nr * __uint_as_float(u0[j] & 0xffff0000u);
            acc[8 + 2*j]     += nr * __uint_as_float(u1[j] << 16);
            acc[8 + 2*j + 1] += nr * __uint_as_float(u1[j] & 0xffff0000u);
        }
    }
#pragma unroll
    for (int j = 0; j < 16; j++) {
        acc[j] += __shfl_xor(acc[j], 8);
        acc[j] += __shfl_xor(acc[j], 16);
        acc[j] += __shfl_xor(acc[j], 32);
    }
    if (q == 0) {
        float dn = dinv[node];
        uint4 o0, o1;
        unsigned* p0 = &o0.x;
        unsigned* p1 = &o1.x;
#pragma unroll
        for (int j = 0; j < 4; j++) {
            p0[j] = f2bf(acc[2*j] * dn)   | ((unsigned)f2bf(acc[2*j+1] * dn) << 16);
            p1[j] = f2bf(acc[8+2*j] * dn) | ((unsigned)f2bf(acc[8+2*j+1] * dn) << 16);
        }
        uint4* op = (uint4*)(aggx + (size_t)node * FEAT + fl * 16);
        op[0] = o0;
        op[1] = o1;
    }
}

// ---------------- MFMA GEMM + gates + output, 64 nodes per block --------------
__global__ __launch_bounds__(256)
void k_post3(const unsigned short* __restrict__ aggx, const unsigned short* __restrict__ WB,
             const float* __restrict__ bfold_ext, const float* __restrict__ WoutZ,
             const float* __restrict__ bout, float* __restrict__ out, int N) {
    __shared__ unsigned short At[64 * 136];   // 128 + 8 pad
    __shared__ float red[64 * 4];
    int t = threadIdx.x;
    int lane = t & 63;
    int w = __builtin_amdgcn_readfirstlane(t >> 6);
    long long base = (long long)blockIdx.x * 64;

    for (int it = 0; it < 4; it++) {
        int idx = it * 256 + t;
        int row = idx >> 4, c16 = idx & 15;
        long long grow = base + row;
        uint4 v = make_uint4(0u, 0u, 0u, 0u);
        if (grow < N) v = *(const uint4*)(aggx + grow * FEAT + c16 * 8);
        *(uint4*)(At + row * 136 + c16 * 8) = v;
    }
    __syncthreads();

    int l15 = lane & 15, lhi = lane >> 4;
    int tadd = 2 * w;
    f32x4 acc[4][4];
#pragma unroll
    for (int ti = 0; ti < 4; ti++)
#pragma unroll
        for (int mi = 0; mi < 4; mi++) acc[ti][mi] = (f32x4)0.f;

    const int tiles[4] = {tadd, tadd + 1, tadd + 8, tadd + 9};
#pragma unroll
    for (int ks = 0; ks < 4; ks++) {
        short8 a[4];
#pragma unroll
        for (int mi = 0; mi < 4; mi++)
            a[mi] = *(const short8*)(At + (mi * 16 + l15) * 136 + ks * 32 + lhi * 8);
        short8 b[4];
#pragma unroll
        for (int ti = 0; ti < 4; ti++)
            b[ti] = *(const short8*)(WB + (((tiles[ti] * 4 + ks) * 64 + lane) << 3));
#pragma unroll
        for (int ti = 0; ti < 4; ti++)
#pragma unroll
            for (int mi = 0; mi < 4; mi++)
                acc[ti][mi] = __builtin_amdgcn_mfma_f32_16x16x32_bf16(
                    a[mi], b[ti], acc[ti][mi], 0, 0, 0);
    }

    float partial[4][4];
#pragma unroll
    for (int mi = 0; mi < 4; mi++)
#pragma unroll
        for (int r = 0; r < 4; r++) partial[mi][r] = 0.f;
#pragma unroll
    for (int d = 0; d < 2; d++) {
        int zcol = (tadd + d) * 16 + l15;
        float bz = bfold_ext[zcol];
        float bh = bfold_ext[zcol + 128];
        float wo = WoutZ[zcol];
#pragma unroll
        for (int mi = 0; mi < 4; mi++)
#pragma unroll
            for (int r = 0; r < 4; r++) {
                float az = acc[d][mi][r] + bz;
                float ah = acc[d + 2][mi][r] + bh;
                float z  = 1.f / (1.f + expf(-az));
                float ht = tanhf(ah);
                float h  = (1.f - z) * ht;
                h = h > 0.f ? h : 0.f;
                partial[mi][r] += h * wo;
            }
    }
#pragma unroll
    for (int mi = 0; mi < 4; mi++)
#pragma unroll
        for (int r = 0; r < 4; r++) {
            float p = partial[mi][r];
            p += __shfl_xor(p, 1);
            p += __shfl_xor(p, 2);
            p += __shfl_xor(p, 4);
            p += __shfl_xor(p, 8);
            partial[mi][r] = p;
        }
    if (l15 == 0) {
#pragma unroll
        for (int mi = 0; mi < 4; mi++)
#pragma unroll
            for (int r = 0; r < 4; r++)
                red[(mi * 16 + lhi * 4 + r) * 4 + w] = partial[mi][r];
    }
    __syncthreads();
    if (t < 64) {
        long long node = base + t;
        if (node < N)
            out[node] = red[t * 4] + red[t * 4 + 1] + red[t * 4 + 2] + red[t * 4 + 3]
                      + bout[0];
    }
}

// ---------------- launcher ----------------
extern "C" void kernel_launch(void* const* d_in, const int* in_sizes, int n_in,
                              void* d_out, int out_size, void* d_ws, size_t ws_size,
                              hipStream_t stream) {
    const float* x    = (const float*)d_in[0];
    const void*  ei   = d_in[1];
    const float* ew   = (const float*)d_in[2];
    const float* Wcz  = (const float*)d_in[3];
    const float* bcz  = (const float*)d_in[4];
    // d_in[5], d_in[6] (Wcr, bcr) dead: R only multiplies H0 == 0
    const float* Wch  = (const float*)d_in[7];
    const float* bch  = (const float*)d_in[8];
    const float* Wlz  = (const float*)d_in[9];
    const float* blz  = (const float*)d_in[10];
    // d_in[11], d_in[12] (Wlr, blr) dead too
    const float* Wlh  = (const float*)d_in[13];
    const float* blh  = (const float*)d_in[14];
    const float* Wout = (const float*)d_in[15];
    const float* bout = (const float*)d_in[16];
    float* out = (float*)d_out;

    int N = in_sizes[0] / FEAT;   // 100000
    int E = in_sizes[2];          // 1600000
    int NB = (N + 255) >> 8;      // 391 buckets of 256 nodes (NB <= 1024)
    int nblocksA = (E + CHUNK - 1) / CHUNK;   // 782

    char* p = (char*)d_ws;
    auto alloc = [&](size_t bytes) -> char* {
        char* r = p;
        p += (bytes + 255) & ~(size_t)255;
        return r;
    };
    float*          dinv        = (float*)alloc((size_t)N * 4);
    int*            cnt         = (int*)  alloc((size_t)N * 4);
    int*            offs        = (int*)  alloc((size_t)N * 4);
    int*            bucketCnt   = (int*)  alloc((size_t)(NB + 1) * 4);
    int*            bucketStart = (int*)  alloc((size_t)(NB + 1) * 4);
    int2*           csr         = (int2*) alloc((size_t)(E + N) * 8);
    unsigned short* xb          = (unsigned short*)alloc((size_t)N * FEAT * 2);
    unsigned short* aggx        = (unsigned short*)alloc((size_t)N * FEAT * 2);
    unsigned short* WB          = (unsigned short*)alloc((size_t)FEAT * 256 * 2);
    float*          bfold_ext   = (float*)alloc(256 * 4);
    float*          WoutZ       = (float*)alloc(128 * 4);
    // aliases into aggx (disjoint lifetimes: sc dead after k_bucket, blockBase
    // dead after k_scatter; aggx first written by k_agg4 afterwards)
    int2* sc        = (int2*)aggx;                          // E*8 = 12.8MB
    int*  blockBase = (int*)((char*)aggx + (size_t)E * 8);  // nblocksA*NB*4 ~ 1.2MB

    hipMemsetAsync(bucketCnt, 0, (size_t)NB * 4, stream);
    k_front<<<1024 + 130 + nblocksA, 256, 0, stream>>>(
        x, (uint4*)xb, N * FEAT / 8,
        Wcz, bcz, Wch, bch, Wlz, blz, Wlh, blh, Wout, WB, bfold_ext, WoutZ,
        ei, bucketCnt, blockBase, NB, E);
    k_scanb<<<1, 1024, 0, stream>>>(bucketCnt, bucketStart, NB);
    k_scatter<<<nblocksA, 512, 0, stream>>>(ei, ew, bucketStart, blockBase, sc, NB, E);
    k_bucket<<<NB, 512, 0, stream>>>(sc, bucketStart, offs, cnt, csr, dinv, N);
    // agg in thirds: keeps each dispatch ~23us so the profiler top-5 window
    // exposes any other kernel that exceeds that
    int Na = 33336, Nb2 = 66668;  // multiples of 4
    k_agg4<<<(Na + 3) / 4, 256, 0, stream>>>(xb, dinv, offs, cnt, csr, aggx, 0, Na);
    k_agg4<<<(Nb2 - Na + 3) / 4, 256, 0, stream>>>(xb, dinv, offs, cnt, csr, aggx, Na, Nb2);
    k_agg4<<<(N - Nb2 + 3) / 4, 256, 0, stream>>>(xb, dinv, offs, cnt, csr, aggx, Nb2, N);
    k_post3<<<(N + 63) / 64, 256, 0, stream>>>(aggx, WB, bfold_ext, WoutZ, bout, out, N);
}

// Round 12
// 284.872 us; speedup vs baseline: 1.1214x; 1.0383x over previous
//
#include <hip/hip_runtime.h>

#define FEAT 128
#define HID  100
#define CHUNK 2048   // edges per chunk-block in hist/scatter passes

typedef __attribute__((ext_vector_type(8))) short short8;
typedef __attribute__((ext_vector_type(4))) float f32x4;

// RNE f32 -> bf16
__device__ __forceinline__ unsigned short f2bf(float f) {
    union { float f; unsigned int u; } v; v.f = f;
    unsigned int r = v.u + 0x7fffu + ((v.u >> 16) & 1u);
    return (unsigned short)(r >> 16);
}

__device__ __forceinline__ int get_edge(const void* ei, int f64, long long pos) {
    return f64 ? (int)((const long long*)ei)[pos] : ((const int*)ei)[pos];
}

// per-wave int64 staging detection: int64 => all sampled high words are 0.
// Must be called with all lanes of the wave active.
__device__ __forceinline__ int detect_f64(const void* ei) {
    const int* p = (const int*)ei;
    unsigned long long b = __ballot(p[2 * (threadIdx.x & 63) + 1] == 0);
    return b == ~0ull;
}

// In-block exclusive scan of bucketCnt[0..NB) into bs[0..NB] (bs[NB]=total).
// Requires blockDim.x >= NB. Call with all threads.
__device__ __forceinline__ void scan_buckets(const int* __restrict__ bucketCnt,
                                             int NB, int* bs) {
    int t = threadIdx.x;
    int v = (t < NB) ? bucketCnt[t] : 0;
    if (t < NB) bs[t] = v;
    __syncthreads();
    for (int off = 1; off < NB; off <<= 1) {
        int tv = (t < NB && t >= off) ? bs[t - off] : 0;
        __syncthreads();
        if (t < NB) bs[t] += tv;
        __syncthreads();
    }
    int incl = (t < NB) ? bs[t] : 0;
    __syncthreads();
    if (t < NB) bs[t] = incl - v;          // exclusive
    if (t == NB - 1) bs[NB] = incl;        // sentinel = E
    __syncthreads();
}

// ---------------- k_front: weight-fold + bucket-histogram ---------------------
// blocks [0,130): fold | [130, 130+nblocksA): hist
__global__ __launch_bounds__(256)
void k_front(const float* __restrict__ Wcz, const float* __restrict__ bcz,
             const float* __restrict__ Wch, const float* __restrict__ bch,
             const float* __restrict__ Wlz, const float* __restrict__ blz,
             const float* __restrict__ Wlh, const float* __restrict__ blh,
             const float* __restrict__ Wout,
             unsigned short* __restrict__ WB, float* __restrict__ bfold_ext,
             float* __restrict__ WoutZ,
             const void* ei, int* __restrict__ bucketCnt,
             int* __restrict__ blockBase, int NB, int E) {
    const int FOLDB = 130;
    __shared__ int hist[1024];
    if (blockIdx.x < FOLDB) {
        int idx = blockIdx.x * 256 + threadIdx.x;
        if (idx < FEAT * 256) {
            int k = idx >> 8, n = idx & 255;
            float val = 0.f;
            if (n < HID) {
                for (int m = 0; m < HID; m++) val += Wcz[k * HID + m] * Wlz[m * HID + n];
            } else if (n >= 128 && n < 128 + HID) {
                int c = n - 128;
                for (int m = 0; m < HID; m++) val += Wch[k * HID + m] * Wlh[m * HID + c];
            }
            int ni = n >> 4, lc = n & 15, ks = k >> 5, hi = (k >> 3) & 3, j = k & 7;
            WB[(((ni * 4 + ks) * 64 + hi * 16 + lc) << 3) + j] = f2bf(val);
        } else if (idx < FEAT * 256 + 256) {
            int c = idx - FEAT * 256;
            float v = 0.f;
            if (c < HID) {
                v = blz[c];
                for (int j = 0; j < HID; j++) v += bcz[j] * Wlz[j * HID + c];
            } else if (c >= 128 && c < 128 + HID) {
                int cc = c - 128;
                v = blh[cc];
                for (int j = 0; j < HID; j++) v += bch[j] * Wlh[j * HID + cc];
            }
            bfold_ext[c] = v;
        } else if (idx < FEAT * 256 + 256 + 128) {
            int c = idx - FEAT * 256 - 256;
            WoutZ[c] = (c < HID) ? Wout[c] : 0.f;
        }
        return;
    }
    // ---- histogram: bucket = dst>>8; 1 global atomic per (block,bucket)
    int f64 = detect_f64(ei);
    int cb = blockIdx.x - FOLDB;
    int t = threadIdx.x;
    for (int i = t; i < NB; i += 256) hist[i] = 0;
    __syncthreads();
    int e0 = cb * CHUNK;
#pragma unroll
    for (int k = 0; k < CHUNK / 256; k++) {
        int e = e0 + k * 256 + t;
        if (e < E) {
            int d = get_edge(ei, f64, (long long)E + e);
            atomicAdd(&hist[d >> 8], 1);
        }
    }
    __syncthreads();
    int* bb = blockBase + (size_t)cb * NB;
    for (int b = t; b < NB; b += 256) {
        int c = hist[b];
        if (c) bb[b] = atomicAdd(&bucketCnt[b], c);
    }
}

// ---------------- k_scvt: x->bf16 convert (blocks <1024) ∥ edge scatter -------
// scatter entry: (src | dlow<<24, w_bits). 512 threads.
__global__ __launch_bounds__(512)
void k_scvt(const float* __restrict__ x, uint4* __restrict__ xb, int n8,
            const void* ei, const float* __restrict__ w,
            const int* __restrict__ bucketCnt, const int* __restrict__ blockBase,
            int2* __restrict__ sc, int NB, int E) {
    const int CVTB = 1024;
    __shared__ int hist[1024];
    __shared__ int bs[1024];
    if (blockIdx.x < CVTB) {
        int stride = CVTB * 512;
        for (int i = blockIdx.x * 512 + threadIdx.x; i < n8; i += stride) {
            float4 a = *(const float4*)(x + (size_t)i * 8);
            float4 b = *(const float4*)(x + (size_t)i * 8 + 4);
            uint4 o;
            o.x = f2bf(a.x) | ((unsigned)f2bf(a.y) << 16);
            o.y = f2bf(a.z) | ((unsigned)f2bf(a.w) << 16);
            o.z = f2bf(b.x) | ((unsigned)f2bf(b.y) << 16);
            o.w = f2bf(b.z) | ((unsigned)f2bf(b.w) << 16);
            xb[i] = o;
        }
        return;
    }
    int f64 = detect_f64(ei);
    int cb = blockIdx.x - CVTB;
    int t = threadIdx.x;
    scan_buckets(bucketCnt, NB, bs);        // bs = bucketStart (redundant per block)
    for (int i = t; i < NB; i += 512) hist[i] = 0;
    __syncthreads();
    int e0 = cb * CHUNK;
    const int* bb = blockBase + (size_t)cb * NB;
    int sA[4], dA[4], wA[4], ok[4];
#pragma unroll
    for (int k = 0; k < 4; k++) {           // phase 1: issue all loads
        int e = e0 + k * 512 + t;
        ok[k] = (e < E);
        if (ok[k]) {
            sA[k] = get_edge(ei, f64, e);
            dA[k] = get_edge(ei, f64, (long long)E + e);
            wA[k] = __float_as_int(w[e]);
        }
    }
#pragma unroll
    for (int k = 0; k < 4; k++) {           // phase 2: ranks + stores
        if (ok[k]) {
            int b = dA[k] >> 8;
            int r = atomicAdd(&hist[b], 1);
            int pos = bs[b] + bb[b] + r;
            long long val = ((long long)wA[k] << 32)
                          | (unsigned)(sA[k] | ((dA[k] & 255) << 24));
            *(long long*)&sc[pos] = val;    // regular store: stays cache-resident
        }
    }
}

// ---------------- k_bucket: per-bucket exact CSR + degsum + self entry --------
__global__ __launch_bounds__(512)
void k_bucket(const int2* __restrict__ sc, const int* __restrict__ bucketCnt,
              int* __restrict__ offs, int* __restrict__ cnt,
              int2* __restrict__ csr, float* __restrict__ dinv, int N, int NB) {
    __shared__ int bs[1024];
    __shared__ int hist[256];
    __shared__ int offsL[256];
    __shared__ int rank[256];
    __shared__ float wsum[256];
    int t = threadIdx.x;
    scan_buckets(bucketCnt, NB, bs);
    int n0 = blockIdx.x << 8;
    int s = bs[blockIdx.x], e = bs[blockIdx.x + 1];
    if (t < 256) { hist[t] = 0; rank[t] = 0; wsum[t] = 0.f; }
    __syncthreads();
    for (int i = s + t; i < e; i += 512)
        atomicAdd(&hist[((unsigned)sc[i].x) >> 24], 1);
    __syncthreads();
    int v = 0;
    if (t < 256) {
        v = (n0 + t < N) ? hist[t] + 1 : 0;   // +1 self-loop slot per real node
        offsL[t] = v;
    }
    __syncthreads();
    for (int off = 1; off < 256; off <<= 1) {
        int tv = (t < 256 && t >= off) ? offsL[t - off] : 0;
        __syncthreads();
        if (t < 256) offsL[t] += tv;
        __syncthreads();
    }
    int myOff = 0, myHist = 0;
    if (t < 256) { myOff = offsL[t] - v; myHist = hist[t]; }
    int csrBase = s + n0;                     // edges + self slots of prior buckets
    if (t < 256 && n0 + t < N) {
        offs[n0 + t] = csrBase + myOff;
        cnt[n0 + t] = v;
    }
    __syncthreads();
    if (t < 256) offsL[t] = myOff;            // exclusive, for scatter
    __syncthreads();
    for (int i = s + t; i < e; i += 512) {
        int2 en = sc[i];
        int dlow = ((unsigned)en.x) >> 24;
        int r = atomicAdd(&rank[dlow], 1);
        csr[csrBase + offsL[dlow] + r] = make_int2(en.x & 0xFFFFFF, en.y);
        atomicAdd(&wsum[dlow], __int_as_float(en.y));
    }
    __syncthreads();
    if (t < 256 && n0 + t < N) {
        dinv[n0 + t] = rsqrtf(1.f + wsum[t]);
        csr[csrBase + myOff + myHist] = make_int2(n0 + t, __float_as_int(1.0f));
    }
}

// ---------------- aggregation: wave/node, 8 edges in flight, bf16 gathers -----
// aggx[d] = dinv[d] * sum_e w_e*dinv[s_e]*x[s_e]   (self edge included in csr)
__global__ __launch_bounds__(256)
void k_agg4(const unsigned short* __restrict__ xb, const float* __restrict__ dinv,
            const int* __restrict__ offs, const int* __restrict__ cnt,
            const int2* __restrict__ csr, unsigned short* __restrict__ aggx, int N) {
    int wid  = __builtin_amdgcn_readfirstlane(threadIdx.x >> 6);
    int lane = threadIdx.x & 63;
    long long node = (long long)blockIdx.x * 4 + wid;
    if (node >= N) return;
    int q  = lane >> 3;        // edge slot 0..7
    int fl = lane & 7;         // feature group: floats fl*16 .. fl*16+15
    float acc[16];
#pragma unroll
    for (int j = 0; j < 16; j++) acc[j] = 0.f;
    int rs = offs[node];
    int c  = cnt[node];
    for (int i = q; i < c; i += 8) {
        int2 e = csr[rs + i];
        float nr = __int_as_float(e.y) * dinv[e.x];   // w * dinv[src]
        const uint4* xp = (const uint4*)(xb + (size_t)e.x * FEAT + fl * 16);
        uint4 v0 = xp[0];
        uint4 v1 = xp[1];
        const unsigned* u0 = &v0.x;
        const unsigned* u1 = &v1.x;
#pragma unroll
        for (int j = 0; j < 4; j++) {
            acc[2*j]         += nr * __uint_as_float(u0[j] << 16);
            acc[2*j + 1]     += nr * __uint_as_float(u0[j] & 0xffff0000u);
            acc[8 + 2*j]     += nr * __uint_as_float(u1[j] << 16);
            acc[8 + 2*j + 1] += nr * __uint_as_float(u1[j] & 0xffff0000u);
        }
    }
#pragma unroll
    for (int j = 0; j < 16; j++) {
        acc[j] += __shfl_xor(acc[j], 8);
        acc[j] += __shfl_xor(acc[j], 16);
        acc[j] += __shfl_xor(acc[j], 32);
    }
    if (q == 0) {
        float dn = dinv[node];
        uint4 o0, o1;
        unsigned* p0 = &o0.x;
        unsigned* p1 = &o1.x;
#pragma unroll
        for (int j = 0; j < 4; j++) {
            p0[j] = f2bf(acc[2*j] * dn)   | ((unsigned)f2bf(acc[2*j+1] * dn) << 16);
            p1[j] = f2bf(acc[8+2*j] * dn) | ((unsigned)f2bf(acc[8+2*j+1] * dn) << 16);
        }
        uint4* op = (uint4*)(aggx + (size_t)node * FEAT + fl * 16);
        op[0] = o0;
        op[1] = o1;
    }
}

// ---------------- MFMA GEMM + gates + output, 64 nodes per block --------------
__global__ __launch_bounds__(256)
void k_post3(const unsigned short* __restrict__ aggx, const unsigned short* __restrict__ WB,
             const float* __restrict__ bfold_ext, const float* __restrict__ WoutZ,
             const float* __restrict__ bout, float* __restrict__ out, int N) {
    __shared__ unsigned short At[64 * 136];   // 128 + 8 pad
    __shared__ float red[64 * 4];
    int t = threadIdx.x;
    int lane = t & 63;
    int w = __builtin_amdgcn_readfirstlane(t >> 6);
    long long base = (long long)blockIdx.x * 64;

    for (int it = 0; it < 4; it++) {
        int idx = it * 256 + t;
        int row = idx >> 4, c16 = idx & 15;
        long long grow = base + row;
        uint4 v = make_uint4(0u, 0u, 0u, 0u);
        if (grow < N) v = *(const uint4*)(aggx + grow * FEAT + c16 * 8);
        *(uint4*)(At + row * 136 + c16 * 8) = v;
    }
    __syncthreads();

    int l15 = lane & 15, lhi = lane >> 4;
    int tadd = 2 * w;
    f32x4 acc[4][4];
#pragma unroll
    for (int ti = 0; ti < 4; ti++)
#pragma unroll
        for (int mi = 0; mi < 4; mi++) acc[ti][mi] = (f32x4)0.f;

    const int tiles[4] = {tadd, tadd + 1, tadd + 8, tadd + 9};
#pragma unroll
    for (int ks = 0; ks < 4; ks++) {
        short8 a[4];
#pragma unroll
        for (int mi = 0; mi < 4; mi++)
            a[mi] = *(const short8*)(At + (mi * 16 + l15) * 136 + ks * 32 + lhi * 8);
        short8 b[4];
#pragma unroll
        for (int ti = 0; ti < 4; ti++)
            b[ti] = *(const short8*)(WB + (((tiles[ti] * 4 + ks) * 64 + lane) << 3));
#pragma unroll
        for (int ti = 0; ti < 4; ti++)
#pragma unroll
            for (int mi = 0; mi < 4; mi++)
                acc[ti][mi] = __builtin_amdgcn_mfma_f32_16x16x32_bf16(
                    a[mi], b[ti], acc[ti][mi], 0, 0, 0);
    }

    float partial[4][4];
#pragma unroll
    for (int mi = 0; mi < 4; mi++)
#pragma unroll
        for (int r = 0; r < 4; r++) partial[mi][r] = 0.f;
#pragma unroll
    for (int d = 0; d < 2; d++) {
        int zcol = (tadd + d) * 16 + l15;
        float bz = bfold_ext[zcol];
        float bh = bfold_ext[zcol + 128];
        float wo = WoutZ[zcol];
#pragma unroll
        for (int mi = 0; mi < 4; mi++)
#pragma unroll
            for (int r = 0; r < 4; r++) {
                float az = acc[d][mi][r] + bz;
                float ah = acc[d + 2][mi][r] + bh;
                float z  = 1.f / (1.f + expf(-az));
                float ht = tanhf(ah);
                float h  = (1.f - z) * ht;
                h = h > 0.f ? h : 0.f;
                partial[mi][r] += h * wo;
            }
    }
#pragma unroll
    for (int mi = 0; mi < 4; mi++)
#pragma unroll
        for (int r = 0; r < 4; r++) {
            float p = partial[mi][r];
            p += __shfl_xor(p, 1);
            p += __shfl_xor(p, 2);
            p += __shfl_xor(p, 4);
            p += __shfl_xor(p, 8);
            partial[mi][r] = p;
        }
    if (l15 == 0) {
#pragma unroll
        for (int mi = 0; mi < 4; mi++)
#pragma unroll
            for (int r = 0; r < 4; r++)
                red[(mi * 16 + lhi * 4 + r) * 4 + w] = partial[mi][r];
    }
    __syncthreads();
    if (t < 64) {
        long long node = base + t;
        if (node < N)
            out[node] = red[t * 4] + red[t * 4 + 1] + red[t * 4 + 2] + red[t * 4 + 3]
                      + bout[0];
    }
}

// ---------------- launcher ----------------
extern "C" void kernel_launch(void* const* d_in, const int* in_sizes, int n_in,
                              void* d_out, int out_size, void* d_ws, size_t ws_size,
                              hipStream_t stream) {
    const float* x    = (const float*)d_in[0];
    const void*  ei   = d_in[1];
    const float* ew   = (const float*)d_in[2];
    const float* Wcz  = (const float*)d_in[3];
    const float* bcz  = (const float*)d_in[4];
    // d_in[5], d_in[6] (Wcr, bcr) dead: R only multiplies H0 == 0
    const float* Wch  = (const float*)d_in[7];
    const float* bch  = (const float*)d_in[8];
    const float* Wlz  = (const float*)d_in[9];
    const float* blz  = (const float*)d_in[10];
    // d_in[11], d_in[12] (Wlr, blr) dead too
    const float* Wlh  = (const float*)d_in[13];
    const float* blh  = (const float*)d_in[14];
    const float* Wout = (const float*)d_in[15];
    const float* bout = (const float*)d_in[16];
    float* out = (float*)d_out;

    int N = in_sizes[0] / FEAT;   // 100000
    int E = in_sizes[2];          // 1600000
    int NB = (N + 255) >> 8;      // 391 buckets of 256 nodes (NB <= 512 required)
    int nblocksA = (E + CHUNK - 1) / CHUNK;   // 782

    char* p = (char*)d_ws;
    auto alloc = [&](size_t bytes) -> char* {
        char* r = p;
        p += (bytes + 255) & ~(size_t)255;
        return r;
    };
    float*          dinv        = (float*)alloc((size_t)N * 4);
    int*            cnt         = (int*)  alloc((size_t)N * 4);
    int*            offs        = (int*)  alloc((size_t)N * 4);
    int*            bucketCnt   = (int*)  alloc((size_t)(NB + 1) * 4);
    int2*           csr         = (int2*) alloc((size_t)(E + N) * 8);
    unsigned short* xb          = (unsigned short*)alloc((size_t)N * FEAT * 2);
    unsigned short* aggx        = (unsigned short*)alloc((size_t)N * FEAT * 2);
    unsigned short* WB          = (unsigned short*)alloc((size_t)FEAT * 256 * 2);
    float*          bfold_ext   = (float*)alloc(256 * 4);
    float*          WoutZ       = (float*)alloc(128 * 4);
    // aliases into aggx (disjoint lifetimes: sc dead after k_bucket, blockBase
    // dead after k_scvt; aggx first written by k_agg4 afterwards)
    int2* sc        = (int2*)aggx;                          // E*8 = 12.8MB
    int*  blockBase = (int*)((char*)aggx + (size_t)E * 8);  // nblocksA*NB*4 ~ 1.2MB

    hipMemsetAsync(bucketCnt, 0, (size_t)NB * 4, stream);
    k_front<<<130 + nblocksA, 256, 0, stream>>>(
        Wcz, bcz, Wch, bch, Wlz, blz, Wlh, blh, Wout, WB, bfold_ext, WoutZ,
        ei, bucketCnt, blockBase, NB, E);
    k_scvt<<<1024 + nblocksA, 512, 0, stream>>>(
        x, (uint4*)xb, N * FEAT / 8, ei, ew, bucketCnt, blockBase, sc, NB, E);
    k_bucket<<<NB, 512, 0, stream>>>(sc, bucketCnt, offs, cnt, csr, dinv, N, NB);
    k_agg4<<<(N + 3) / 4, 256, 0, stream>>>(xb, dinv, offs, cnt, csr, aggx, N);
    k_post3<<<(N + 63) / 64, 256, 0, stream>>>(aggx, WB, bfold_ext, WoutZ, bout, out, N);
}